// Round 1
// baseline (1351.555 us; speedup 1.0000x reference)
//
#include <hip/hip_runtime.h>
#include <stdint.h>
#include <string.h>

// Problem dims (fixed by the reference)
#define BDIM   4096
#define INDIM  1024
#define XDIM   2048
#define OUTDIM 512
#define MCH    (BDIM / 16)   // 256 row-chunks along M for packed activations

#define LO_SCALE 2048.0f         // 2^11: lifts fp16 lo-plane out of subnormals
#define INV_LO_SCALE (1.0f / 2048.0f)

typedef _Float16 f16x8 __attribute__((ext_vector_type(8)));
typedef float f32x4 __attribute__((ext_vector_type(4)));
typedef unsigned short u16x8 __attribute__((ext_vector_type(8)));
typedef unsigned short u16x4 __attribute__((ext_vector_type(4)));

__device__ __forceinline__ unsigned short h2u(_Float16 h) {
  unsigned short u;
  memcpy(&u, &h, 2);
  return u;
}

// split f32 into hi fp16 + scaled-lo fp16 (combined ~22 mantissa bits)
__device__ __forceinline__ void split_h(float v, unsigned short& h,
                                        unsigned short& l) {
  _Float16 hh = (_Float16)v;                       // RTNE
  float r = v - (float)hh;                         // exact
  _Float16 ll = (_Float16)(r * LO_SCALE);          // |r|*2^11 <= |v|, no inf
  h = h2u(hh);
  l = h2u(ll);
}

// async global->LDS, 16B per lane; LDS dest wave-uniform base + lane*16
__device__ __forceinline__ void gld_lds16(const void* g, void* l) {
  __builtin_amdgcn_global_load_lds(
      (const __attribute__((address_space(1))) uint32_t*)g,
      (__attribute__((address_space(3))) uint32_t*)l, 16, 0, 0);
}

// fused RandomActivation + clip (relu/sigmoid/tanh/leaky(.1)/selu), libm-grade
__device__ __forceinline__ float rand_act(float v, int a, float mo) {
  float r;
  if (a == 0) {
    r = fmaxf(v, 0.0f);
  } else if (a == 1) {
    r = 1.0f / (1.0f + expf(-v));
  } else if (a == 2) {
    r = tanhf(v);
  } else if (a == 3) {
    r = (v >= 0.0f) ? v : 0.1f * v;
  } else {  // selu (matches jax: scale * where(v>0, v, alpha*expm1(v)))
    r = (v > 0.0f) ? 1.0507009873554805f * v
                   : 1.7580993408473766f * expm1f(v);
  }
  return fminf(r, mo);
}

// ---------------------------------------------------------------------------
// PACKED LAYOUT: tensor X[rows][K] is stored as
//   packed[k/32][row/16][lane(64)][8 halfs],
// lane = quad*16 + m16 holding X[chunkrow*16 + m16][kstep*32 + quad*8 + j].
// Each (kstep,chunk) = contiguous 1 KB: staging DMA is consecutive-lane-
// contiguous AND compute ds_read_b128 is contiguous (zero conflicts).
// Concat along K = packed tensors back-to-back.
// ---------------------------------------------------------------------------

// x[BDIM][Kin] f32 row-major -> packed hi/lo planes. grid(Kin/32, BDIM/64)x256
__global__ void pack_x(const float* __restrict__ s,
                       unsigned short* __restrict__ dh,
                       unsigned short* __restrict__ dl, int Kin) {
  int ks = blockIdx.x;
  int mblk = blockIdx.y;
  int cc = threadIdx.x >> 6;        // chunk within 64-row group
  int lane = threadIdx.x & 63;
  int m16 = lane & 15, quad = lane >> 4;
  int row = mblk * 64 + cc * 16 + m16;
  const float* src = s + (size_t)row * Kin + ks * 32 + quad * 8;
  size_t o = ((size_t)ks * MCH + mblk * 4 + cc) * 512 + lane * 8;
  float4 v0 = *(const float4*)src;
  float4 v1 = *(const float4*)(src + 4);
  float vs[8] = {v0.x, v0.y, v0.z, v0.w, v1.x, v1.y, v1.z, v1.w};
  u16x8 vh, vl;
#pragma unroll
  for (int j = 0; j < 8; j++) {
    unsigned short h, l;
    split_h(vs[j], h, l);
    vh[j] = h;
    vl[j] = l;
  }
  *(u16x8*)(dh + o) = vh;
  *(u16x8*)(dl + o) = vl;
}

// W[K][N] f32 row-major -> packed-BT hi/lo (rows=N, Kdim=K).
// grid(N/32, K/32), block(32,8).
__global__ void pack_w(const float* __restrict__ W,
                       unsigned short* __restrict__ dh,
                       unsigned short* __restrict__ dl, int K, int N) {
  __shared__ float t[32][33];       // t[k'][n']
  int n0 = blockIdx.x * 32, k0 = blockIdx.y * 32;
  int tx = threadIdx.x, ty = threadIdx.y;
#pragma unroll
  for (int i = 0; i < 32; i += 8)
    t[ty + i][tx] = W[(size_t)(k0 + ty + i) * N + n0 + tx];
  __syncthreads();
  int tt = ty * 32 + tx;            // 0..255
  int ci = tt >> 7;                 // n-chunk 0/1
  int rem = tt & 127;
  int lane = rem >> 1;
  int j4 = (rem & 1) * 4;
  int m16 = lane & 15, quad = lane >> 4;
  size_t o = ((size_t)(k0 >> 5) * (N >> 4) + (n0 >> 4) + ci) * 512 +
             lane * 8 + j4;
  u16x4 vh, vl;
#pragma unroll
  for (int jj = 0; jj < 4; jj++) {
    float v = t[quad * 8 + j4 + jj][ci * 16 + m16];
    unsigned short h, l;
    split_h(v, h, l);
    vh[jj] = h;
    vl[jj] = l;
  }
  *(u16x4*)(dh + o) = vh;
  *(u16x4*)(dl + o) = vl;
}

// C[M,N] = act( A[M,K] @ BT[N,K]^T + bias ), split-fp16 (3-term) precision.
// acc1 = hi*hi; acc2 = hi*lo' + lo'*hi at scale 2^11. Final = acc1+acc2/2^11.
//
// Round-10 structure: counted-vmcnt deep pipeline (T3+T4+T5).
//  - 3 LDS buffers (24 KB), staging issued TWO K-steps ahead; the barrier
//    publishing buf[ks+1] uses s_waitcnt vmcnt(6) -> the ks+2 stage and the
//    ks+1 B-loads stay in flight across the barrier (never drain to 0).
//  - ONE raw s_barrier per K-step (was 2 full-drain __syncthreads).
//  - A-fragments register-double-buffered: the 8 ds_read_b128 for step ks+1
//    are issued right after the barrier and consumed one phase later (the
//    lgkmcnt wait is a no-op); they overlap the phase-3 MFMA cluster.
//  - B register-double-buffered; loaded one full K-step before use.
//  - s_setprio(1) around the MFMA clusters; sched_barrier(0) pins regions.
// Block tile 64x128, BK=32, 4 waves (wave-tile 64x32). Grid (N/128, M/64),
// XCD-swizzled so each XCD owns contiguous N-strips (B slice L2-resident).
template <bool OUT_F16>
__global__ __launch_bounds__(256, 2) void gemm_split_act(
    const short* __restrict__ A1h, const short* __restrict__ A1l,
    const short* __restrict__ A2h, const short* __restrict__ A2l,
    const short* __restrict__ BTh, const short* __restrict__ BTl,
    const float* __restrict__ bias, const float* __restrict__ mo,
    const int* __restrict__ aid, unsigned short* __restrict__ Ch,
    unsigned short* __restrict__ Cl, float* __restrict__ Cf, int N, int K,
    int Ksplit) {
  __shared__ short lds0[8 * 512];   // 8 KB each: chunks 0-3 hi, 4-7 lo
  __shared__ short lds1[8 * 512];
  __shared__ short lds2[8 * 512];

  const int tid = threadIdx.x;
  const int lane = tid & 63;
  const int wave = tid >> 6;        // 0..3 = n-strip of wave
  const int m16 = lane & 15, quad = lane >> 4;

  // bijective XCD swizzle: group blocks by N-strip per XCD (B reuse in L2).
  // gridDim.y == BDIM/64 == 64 always; nwg divisible by 8 for all layers.
  const int nwg = gridDim.x * 64;
  const int lin = blockIdx.y * gridDim.x + blockIdx.x;
  const int cpx = nwg >> 3;
  const int virt = (lin & 7) * cpx + (lin >> 3);
  const int blockN = (virt >> 6) * 128;   // bx-major decode
  const int blockM = (virt & 63) * 64;

  f32x4 acc1[4][2];  // hi*hi
  f32x4 acc2[4][2];  // (hi*lo' + lo'*hi), scale 2^11
#pragma unroll
  for (int i = 0; i < 4; i++)
#pragma unroll
    for (int j = 0; j < 2; j++) {
      acc1[i][j] = (f32x4){0.f, 0.f, 0.f, 0.f};
      acc2[i][j] = (f32x4){0.f, 0.f, 0.f, 0.f};
    }

  const int KSTEPS = K >> 5;        // 32/64/128 — always even, >= 32
  const int KS1 = Ksplit >> 5;

  // ---- staging state (strength-reduced; stage calls are monotone k=0,1,..)
  const short* sAh = A1h;
  const short* sAl = A1l;
  const size_t aBase0 = (size_t)(blockM >> 4) * 512 + lane * 8;
  size_t aOff = aBase0;
  int stageK = 0;
  auto stageNext = [&](short* dst) {   // 2 x gld_lds (1 KB each) per wave
#pragma unroll
    for (int s = 0; s < 2; s++) {
      int g = wave * 2 + s;            // 0..7
      const short* plane = (g < 4) ? sAh : sAl;
      gld_lds16(plane + aOff + (g & 3) * 512, dst + g * 512);
    }
    aOff += (size_t)MCH * 512;
    if (++stageK == KS1) { sAh = A2h; sAl = A2l; aOff = aBase0; }
  };

  // ---- B-load state (4 x 16B loads per wave per K-step)
  size_t bOff = ((size_t)(blockN >> 4) + wave * 2) * 512 + lane * 8;
  const size_t bStride = (size_t)N * 32;
  auto loadBNext = [&](f16x8 (&bH)[2], f16x8 (&bL)[2]) {
    bH[0] = *(const f16x8*)(BTh + bOff);
    bH[1] = *(const f16x8*)(BTh + bOff + 512);
    bL[0] = *(const f16x8*)(BTl + bOff);
    bL[1] = *(const f16x8*)(BTl + bOff + 512);
    bOff += bStride;
  };

  f16x8 a0h[4], a0l[4], a1h[4], a1l[4];
  f16x8 b0H[2], b0L[2], b1H[2], b1L[2];

  auto ldsRead = [&](const short* src, f16x8 (&aH)[4], f16x8 (&aL)[4]) {
#pragma unroll
    for (int t = 0; t < 4; t++)
      aH[t] = *(const f16x8*)&src[t * 512 + lane * 8];
#pragma unroll
    for (int t = 0; t < 4; t++)
      aL[t] = *(const f16x8*)&src[(4 + t) * 512 + lane * 8];
  };

  auto ph12 = [&](f16x8 (&aH)[4], f16x8 (&bH)[2], f16x8 (&bL)[2]) {
    __builtin_amdgcn_s_setprio(1);
#pragma unroll
    for (int i = 0; i < 4; i++)
#pragma unroll
      for (int j = 0; j < 2; j++)
        acc1[i][j] = __builtin_amdgcn_mfma_f32_16x16x32_f16(aH[i], bH[j],
                                                            acc1[i][j], 0, 0, 0);
#pragma unroll
    for (int i = 0; i < 4; i++)
#pragma unroll
      for (int j = 0; j < 2; j++)
        acc2[i][j] = __builtin_amdgcn_mfma_f32_16x16x32_f16(aH[i], bL[j],
                                                            acc2[i][j], 0, 0, 0);
    __builtin_amdgcn_s_setprio(0);
  };
  auto ph3 = [&](f16x8 (&aL)[4], f16x8 (&bH)[2]) {
    __builtin_amdgcn_s_setprio(1);
#pragma unroll
    for (int i = 0; i < 4; i++)
#pragma unroll
      for (int j = 0; j < 2; j++)
        acc2[i][j] = __builtin_amdgcn_mfma_f32_16x16x32_f16(aL[i], bH[j],
                                                            acc2[i][j], 0, 0, 0);
    __builtin_amdgcn_s_setprio(0);
  };

#define SB0 __builtin_amdgcn_sched_barrier(0)

  // One K-step. VMEM ledger (per wave, old->new) entering the iter:
  //   L(ks)=4, S(ks+1)=2   (compiler auto-emits vmcnt(2) before ph12's B use)
  // after loadB+stage: S(ks+1)2, L(ks+1)4, S(ks+2)2 = 8
  //   -> vmcnt(6) retires exactly S(ks+1) -> barrier publishes buf[ks+1];
  //      6 ops stay in flight across the barrier.
  auto ITER = [&](f16x8 (&aHc)[4], f16x8 (&aLc)[4], f16x8 (&aHn)[4],
                  f16x8 (&aLn)[4], f16x8 (&bHc)[2], f16x8 (&bLc)[2],
                  f16x8 (&bHn)[2], f16x8 (&bLn)[2], const short* src,
                  short* dst, bool doStage) {
    SB0;
    ph12(aHc, bHc, bLc);             // 16 MFMA: hi*hi -> acc1, hi*lo' -> acc2
    SB0;
    loadBNext(bHn, bLn);             // B(ks+1) -> regs (used next iter)
    if (doStage) stageNext(dst);     // A(ks+2) -> LDS DMA
    SB0;
    if (doStage)
      asm volatile("s_waitcnt vmcnt(6)" ::: "memory");
    else
      asm volatile("s_waitcnt vmcnt(4)" ::: "memory");
    __builtin_amdgcn_s_barrier();    // publish buf[ks+1]; no drain
    SB0;
    ldsRead(src, aHn, aLn);          // A-frags(ks+1); overlap ph3
    SB0;
    ph3(aLc, bHc);                   // 8 MFMA: lo'*hi -> acc2
    SB0;
  };

  // ---- prologue: stage k=0,1; load B(0); publish buf0; read A-frags(0)
  stageNext(lds0);                   // S0: 2
  loadBNext(b0H, b0L);               // L0: 4
  stageNext(lds1);                   // S1: 2   (outstanding 8)
  asm volatile("s_waitcnt vmcnt(6)" ::: "memory");  // S0 done
  __builtin_amdgcn_s_barrier();
  SB0;
  ldsRead(lds0, a0h, a0l);
  // entering ks=0: outstanding L0(4), S1(2)  ✓ invariant

  short *bs = lds1, *bd = lds2, *bt = lds0;  // iter ks: src=bs, dst=bd
  for (int ks = 0; ks <= KSTEPS - 4; ks += 2) {
    ITER(a0h, a0l, a1h, a1l, b0H, b0L, b1H, b1L, bs, bd, true);
    ITER(a1h, a1l, a0h, a0l, b1H, b1L, b0H, b0L, bd, bt, true);
    short* tmp = bs; bs = bt; bt = bd; bd = tmp;   // (s,d,t) <- (t,s,d)
  }
  // peeled ks = KSTEPS-2 (parity 0): no stage; vmcnt(4) retires S(KSTEPS-1)
  ITER(a0h, a0l, a1h, a1l, b0H, b0L, b1H, b1L, bs, nullptr, false);
  // final ks = KSTEPS-1 (parity 1): compute only
  SB0;
  ph12(a1h, b1H, b1L);
  ph3(a1l, b1H);

  // epilogue: combine accs, bias + per-column activation + clip.
  // C/D map col=lane&15, row=quad*4+reg (m89-verified).
  // OUT_F16 path writes PACKED layout (next layer's A): chunkrow=row>>4,
  // kstep=col>>5, lane'=((col>>3)&3)*16 + (row&15), j'=col&7.
#pragma unroll
  for (int j = 0; j < 2; j++) {
    int col = blockN + wave * 32 + j * 16 + m16;
    float b = bias[col];
    float m = mo[col];
    int a = aid[col];
    size_t kbase = OUT_F16 ? ((size_t)(col >> 5) * MCH) * 512 +
                                 (size_t)((col >> 3) & 3) * 128 + (col & 7)
                           : 0;
#pragma unroll
    for (int i = 0; i < 4; i++) {
#pragma unroll
      for (int r = 0; r < 4; r++) {
        int row = blockM + i * 16 + quad * 4 + r;
        float s = acc1[i][j][r] + acc2[i][j][r] * INV_LO_SCALE;
        float v = rand_act(s + b, a, m);
        if (OUT_F16) {
          unsigned short h, l;
          split_h(v, h, l);
          size_t pidx = kbase + (size_t)(row >> 4) * 512 + (row & 15) * 8;
          Ch[pidx] = h;
          Cl[pidx] = l;
        } else {
          Cf[(size_t)row * N + col] = v;
        }
      }
    }
  }
}

extern "C" void kernel_launch(void* const* d_in, const int* in_sizes, int n_in,
                              void* d_out, int out_size, void* d_ws,
                              size_t ws_size, hipStream_t stream) {
  (void)in_sizes; (void)n_in; (void)out_size; (void)ws_size;

  const float* x     = (const float*)d_in[0];
  const float* W_in  = (const float*)d_in[1];
  const float* b_in  = (const float*)d_in[2];
  const float* Wh[6] = {(const float*)d_in[3], (const float*)d_in[4],
                        (const float*)d_in[5], (const float*)d_in[6],
                        (const float*)d_in[7], (const float*)d_in[8]};
  const float* bh    = (const float*)d_in[9];
  const float* W_out = (const float*)d_in[10];
  const float* b_out = (const float*)d_in[11];
  const float* mo_in = (const float*)d_in[12];
  const float* mo_h  = (const float*)d_in[13];
  const float* mo_out= (const float*)d_in[14];
  const int* aid_in  = (const int*)d_in[15];
  const int* aid_h   = (const int*)d_in[16];
  const int* aid_out = (const int*)d_in[17];

  const int hin[6] = {XDIM, XDIM, 2 * XDIM, XDIM, 2 * XDIM, XDIM};

  // workspace layout (~264 MB); each tensor = hi plane then lo plane (packed)
  char* p = (char*)d_ws;
  auto take = [&](size_t elems) {
    short* q = (short*)p;
    p += elems * 2 * 2;  // hi + lo, 2B each
    return q;
  };
  short* x_s = take((size_t)BDIM * INDIM);
  size_t xpl = (size_t)BDIM * INDIM;
  short* w_in_s = take((size_t)XDIM * INDIM);
  size_t wpl_in = (size_t)XDIM * INDIM;
  short* w_h_s[6];
  size_t wpl_h[6];
  for (int i = 0; i < 6; i++) {
    wpl_h[i] = (size_t)XDIM * hin[i];
    w_h_s[i] = take(wpl_h[i]);
  }
  short* w_out_s = take((size_t)OUTDIM * XDIM);
  size_t wpl_out = (size_t)OUTDIM * XDIM;
  const size_t apl = (size_t)BDIM * XDIM;  // activation plane
  short* actA = take(apl);
  short* actB = take(apl);
  short* actC = take(apl);

  // 1) pack x -> hi/lo fp16 packed
  pack_x<<<dim3(INDIM / 32, BDIM / 64), dim3(256), 0, stream>>>(
      x, (unsigned short*)x_s, (unsigned short*)(x_s + xpl), INDIM);
  // 2) pack all weights: W(K,N) -> packed BT(rows=N, Kdim=K) hi/lo
  pack_w<<<dim3(XDIM / 32, INDIM / 32), dim3(32, 8), 0, stream>>>(
      W_in, (unsigned short*)w_in_s, (unsigned short*)(w_in_s + wpl_in), INDIM,
      XDIM);
  for (int i = 0; i < 6; i++)
    pack_w<<<dim3(XDIM / 32, hin[i] / 32), dim3(32, 8), 0, stream>>>(
        Wh[i], (unsigned short*)w_h_s[i],
        (unsigned short*)(w_h_s[i] + wpl_h[i]), hin[i], XDIM);
  pack_w<<<dim3(OUTDIM / 32, XDIM / 32), dim3(32, 8), 0, stream>>>(
      W_out, (unsigned short*)w_out_s, (unsigned short*)(w_out_s + wpl_out),
      XDIM, OUTDIM);

  // 3) GEMM chain with 3 rotating activation buffers
  auto G = [&](const short* A1, size_t a1pl, const short* A2, size_t a2pl,
               const short* W, size_t wpl, const float* bi, const float* m,
               const int* a, short* Cb, float* Cf, int N, int K, int Ks) {
    dim3 grid(N / 128, BDIM / 64);
    const short* A2h = A2;
    const short* A2l = A2 ? A2 + a2pl : nullptr;
    if (Cb)
      gemm_split_act<true><<<grid, 256, 0, stream>>>(
          A1, A1 + a1pl, A2h, A2l, W, W + wpl, bi, m, a, (unsigned short*)Cb,
          (unsigned short*)(Cb + apl), nullptr, N, K, Ks);
    else
      gemm_split_act<false><<<grid, 256, 0, stream>>>(
          A1, A1 + a1pl, A2h, A2l, W, W + wpl, bi, m, a, nullptr, nullptr, Cf,
          N, K, Ks);
  };

  // input layer: outs[0]=actA
  G(x_s, xpl, nullptr, 0, w_in_s, wpl_in, b_in, mo_in, aid_in, actA, nullptr,
    XDIM, INDIM, INDIM);
  // L0: outs[1]=actB
  G(actA, apl, nullptr, 0, w_h_s[0], wpl_h[0], bh + 0 * XDIM, mo_h + 0 * XDIM,
    aid_h + 0 * XDIM, actB, nullptr, XDIM, XDIM, XDIM);
  // L1: outs[2]=actC
  G(actB, apl, nullptr, 0, w_h_s[1], wpl_h[1], bh + 1 * XDIM, mo_h + 1 * XDIM,
    aid_h + 1 * XDIM, actC, nullptr, XDIM, XDIM, XDIM);
  // L2 (concat outs2,outs1): outs[3]=actA
  G(actC, apl, actB, apl, w_h_s[2], wpl_h[2], bh + 2 * XDIM, mo_h + 2 * XDIM,
    aid_h + 2 * XDIM, actA, nullptr, XDIM, 2 * XDIM, XDIM);
  // L3: outs[4]=actB
  G(actA, apl, nullptr, 0, w_h_s[3], wpl_h[3], bh + 3 * XDIM, mo_h + 3 * XDIM,
    aid_h + 3 * XDIM, actB, nullptr, XDIM, XDIM, XDIM);
  // L4 (concat outs4,outs3): outs[5]=actC
  G(actB, apl, actA, apl, w_h_s[4], wpl_h[4], bh + 4 * XDIM, mo_h + 4 * XDIM,
    aid_h + 4 * XDIM, actC, nullptr, XDIM, 2 * XDIM, XDIM);
  // L5: outs[6]=actB
  G(actC, apl, nullptr, 0, w_h_s[5], wpl_h[5], bh + 5 * XDIM, mo_h + 5 * XDIM,
    aid_h + 5 * XDIM, actB, nullptr, XDIM, XDIM, XDIM);
  // output layer -> d_out (fp32, row-major)
  G(actB, apl, nullptr, 0, w_out_s, wpl_out, b_out, mo_out, aid_out, nullptr,
    (float*)d_out, OUTDIM, XDIM, XDIM);
}

// Round 2
// 1225.475 us; speedup vs baseline: 1.1029x; 1.1029x over previous
//
#include <hip/hip_runtime.h>
#include <stdint.h>
#include <string.h>

// Problem dims (fixed by the reference)
#define BDIM   4096
#define INDIM  1024
#define XDIM   2048
#define OUTDIM 512
#define MCH    (BDIM / 16)   // 256 row-chunks along M for packed activations

#define LO_SCALE 2048.0f         // 2^11: lifts fp16 lo-plane out of subnormals
#define INV_LO_SCALE (1.0f / 2048.0f)

typedef _Float16 f16x8 __attribute__((ext_vector_type(8)));
typedef float f32x4 __attribute__((ext_vector_type(4)));
typedef unsigned short u16x8 __attribute__((ext_vector_type(8)));
typedef unsigned short u16x4 __attribute__((ext_vector_type(4)));

__device__ __forceinline__ unsigned short h2u(_Float16 h) {
  unsigned short u;
  memcpy(&u, &h, 2);
  return u;
}

// split f32 into hi fp16 + scaled-lo fp16 (combined ~22 mantissa bits)
__device__ __forceinline__ void split_h(float v, unsigned short& h,
                                        unsigned short& l) {
  _Float16 hh = (_Float16)v;                       // RTNE
  float r = v - (float)hh;                         // exact
  _Float16 ll = (_Float16)(r * LO_SCALE);          // |r|*2^11 <= |v|, no inf
  h = h2u(hh);
  l = h2u(ll);
}

// async global->LDS, 16B per lane; LDS dest wave-uniform base + lane*16
__device__ __forceinline__ void gld_lds16(const void* g, void* l) {
  __builtin_amdgcn_global_load_lds(
      (const __attribute__((address_space(1))) uint32_t*)g,
      (__attribute__((address_space(3))) uint32_t*)l, 16, 0, 0);
}

// fused RandomActivation + clip (relu/sigmoid/tanh/leaky(.1)/selu), libm-grade
__device__ __forceinline__ float rand_act(float v, int a, float mo) {
  float r;
  if (a == 0) {
    r = fmaxf(v, 0.0f);
  } else if (a == 1) {
    r = 1.0f / (1.0f + expf(-v));
  } else if (a == 2) {
    r = tanhf(v);
  } else if (a == 3) {
    r = (v >= 0.0f) ? v : 0.1f * v;
  } else {  // selu (matches jax: scale * where(v>0, v, alpha*expm1(v)))
    r = (v > 0.0f) ? 1.0507009873554805f * v
                   : 1.7580993408473766f * expm1f(v);
  }
  return fminf(r, mo);
}

// ---------------------------------------------------------------------------
// PACKED LAYOUT: tensor X[rows][K] is stored as
//   packed[k/32][row/16][lane(64)][8 halfs],
// lane = quad*16 + m16 holding X[chunkrow*16 + m16][kstep*32 + quad*8 + j].
// Each (kstep,chunk) = contiguous 1 KB: staging DMA is consecutive-lane-
// contiguous AND compute ds_read_b128 is contiguous (zero conflicts).
// Concat along K = packed tensors back-to-back.
// ---------------------------------------------------------------------------

// x[BDIM][Kin] f32 row-major -> packed hi/lo planes. grid(Kin/32, BDIM/64)x256
__global__ void pack_x(const float* __restrict__ s,
                       unsigned short* __restrict__ dh,
                       unsigned short* __restrict__ dl, int Kin) {
  int ks = blockIdx.x;
  int mblk = blockIdx.y;
  int cc = threadIdx.x >> 6;        // chunk within 64-row group
  int lane = threadIdx.x & 63;
  int m16 = lane & 15, quad = lane >> 4;
  int row = mblk * 64 + cc * 16 + m16;
  const float* src = s + (size_t)row * Kin + ks * 32 + quad * 8;
  size_t o = ((size_t)ks * MCH + mblk * 4 + cc) * 512 + lane * 8;
  float4 v0 = *(const float4*)src;
  float4 v1 = *(const float4*)(src + 4);
  float vs[8] = {v0.x, v0.y, v0.z, v0.w, v1.x, v1.y, v1.z, v1.w};
  u16x8 vh, vl;
#pragma unroll
  for (int j = 0; j < 8; j++) {
    unsigned short h, l;
    split_h(vs[j], h, l);
    vh[j] = h;
    vl[j] = l;
  }
  *(u16x8*)(dh + o) = vh;
  *(u16x8*)(dl + o) = vl;
}

// W[K][N] f32 row-major -> packed-BT hi/lo (rows=N, Kdim=K).
// grid(N/32, K/32), block(32,8).
__global__ void pack_w(const float* __restrict__ W,
                       unsigned short* __restrict__ dh,
                       unsigned short* __restrict__ dl, int K, int N) {
  __shared__ float t[32][33];       // t[k'][n']
  int n0 = blockIdx.x * 32, k0 = blockIdx.y * 32;
  int tx = threadIdx.x, ty = threadIdx.y;
#pragma unroll
  for (int i = 0; i < 32; i += 8)
    t[ty + i][tx] = W[(size_t)(k0 + ty + i) * N + n0 + tx];
  __syncthreads();
  int tt = ty * 32 + tx;            // 0..255
  int ci = tt >> 7;                 // n-chunk 0/1
  int rem = tt & 127;
  int lane = rem >> 1;
  int j4 = (rem & 1) * 4;
  int m16 = lane & 15, quad = lane >> 4;
  size_t o = ((size_t)(k0 >> 5) * (N >> 4) + (n0 >> 4) + ci) * 512 +
             lane * 8 + j4;
  u16x4 vh, vl;
#pragma unroll
  for (int jj = 0; jj < 4; jj++) {
    float v = t[quad * 8 + j4 + jj][ci * 16 + m16];
    unsigned short h, l;
    split_h(v, h, l);
    vh[jj] = h;
    vl[jj] = l;
  }
  *(u16x4*)(dh + o) = vh;
  *(u16x4*)(dl + o) = vl;
}

// C[M,N] = act( A[M,K] @ BT[N,K]^T + bias ), split-fp16 (3-term) precision.
// acc1 = hi*hi; acc2 = hi*lo' + lo'*hi at scale 2^11. Final = acc1+acc2/2^11.
//
// Round-11 structure (R10 post-mortem applied):
//  - LINEAR block order restored (R10's XCD swizzle raised FETCH 318->541MB
//    and turned B loads into HBM-latency misses; x-fastest order keeps
//    A-panels and B re-reads L2/L3-warm).
//  - counted-vmcnt single-barrier pipeline kept: 3 LDS buffers (24 KB),
//    A-DMA issued TWO K-steps ahead, B regs double-buffered one step ahead.
//    Per K-step ledger: enter {L(ks)4,S(ks+1)2}; +{L(ks+1)4,S(ks+2)2}=12;
//    vmcnt(8) before MFMA (B ready); vmcnt(6)+s_barrier at end (publishes
//    buf[ks+1], 6 ops stay in flight). Never drains to 0 in the loop.
//  - NO A-register double-buffer (R10's 64-VGPR cost killed occupancy):
//    A-frags are plain ds_reads at iter top; compiler emits minimal lgkmcnt.
//  - __launch_bounds__(256,3): 3 blocks/CU (12 waves) for TLP.
// Block tile 64x128, BK=32, 4 waves (wave-tile 64x32). Grid (N/128, M/64).
template <bool OUT_F16>
__global__ __launch_bounds__(256, 3) void gemm_split_act(
    const short* __restrict__ A1h, const short* __restrict__ A1l,
    const short* __restrict__ A2h, const short* __restrict__ A2l,
    const short* __restrict__ BTh, const short* __restrict__ BTl,
    const float* __restrict__ bias, const float* __restrict__ mo,
    const int* __restrict__ aid, unsigned short* __restrict__ Ch,
    unsigned short* __restrict__ Cl, float* __restrict__ Cf, int N, int K,
    int Ksplit) {
  __shared__ short lds0[8 * 512];   // 8 KB each: chunks 0-3 hi, 4-7 lo
  __shared__ short lds1[8 * 512];
  __shared__ short lds2[8 * 512];

  const int tid = threadIdx.x;
  const int lane = tid & 63;
  const int wave = tid >> 6;        // 0..3 = n-strip of wave
  const int m16 = lane & 15, quad = lane >> 4;

  const int blockN = blockIdx.x * 128;   // linear order (proven locality)
  const int blockM = blockIdx.y * 64;

  f32x4 acc1[4][2];  // hi*hi
  f32x4 acc2[4][2];  // (hi*lo' + lo'*hi), scale 2^11
#pragma unroll
  for (int i = 0; i < 4; i++)
#pragma unroll
    for (int j = 0; j < 2; j++) {
      acc1[i][j] = (f32x4){0.f, 0.f, 0.f, 0.f};
      acc2[i][j] = (f32x4){0.f, 0.f, 0.f, 0.f};
    }

  const int KSTEPS = K >> 5;        // 32/64/128 — always even, >= 32
  const int KS1 = Ksplit >> 5;

  // ---- staging state (strength-reduced; stage calls are monotone k=0,1,..)
  const short* sAh = A1h;
  const short* sAl = A1l;
  const size_t aBase0 = (size_t)(blockM >> 4) * 512 + lane * 8;
  size_t aOff = aBase0;
  int stageK = 0;
  auto stageNext = [&](short* dst) {   // 2 x gld_lds (1 KB each) per wave
#pragma unroll
    for (int s = 0; s < 2; s++) {
      int g = wave * 2 + s;            // 0..7
      const short* plane = (g < 4) ? sAh : sAl;
      gld_lds16(plane + aOff + (g & 3) * 512, dst + g * 512);
    }
    aOff += (size_t)MCH * 512;
    if (++stageK == KS1) { sAh = A2h; sAl = A2l; aOff = aBase0; }
  };

  // ---- B-load state (4 x 16B loads per wave per K-step)
  size_t bOff = ((size_t)(blockN >> 4) + wave * 2) * 512 + lane * 8;
  const size_t bStride = (size_t)N * 32;
  auto loadBNext = [&](f16x8 (&bH)[2], f16x8 (&bL)[2]) {
    bH[0] = *(const f16x8*)(BTh + bOff);
    bH[1] = *(const f16x8*)(BTh + bOff + 512);
    bL[0] = *(const f16x8*)(BTl + bOff);
    bL[1] = *(const f16x8*)(BTl + bOff + 512);
    bOff += bStride;
  };

  f16x8 aH[4], aL[4];               // single A-frag set (no reg dbuf)
  f16x8 b0H[2], b0L[2], b1H[2], b1L[2];

  auto ldsRead = [&](const short* src) {
#pragma unroll
    for (int t = 0; t < 4; t++)
      aH[t] = *(const f16x8*)&src[t * 512 + lane * 8];
#pragma unroll
    for (int t = 0; t < 4; t++)
      aL[t] = *(const f16x8*)&src[(4 + t) * 512 + lane * 8];
  };

  auto ph12 = [&](f16x8 (&bH)[2], f16x8 (&bL)[2]) {
    __builtin_amdgcn_s_setprio(1);
#pragma unroll
    for (int i = 0; i < 4; i++)
#pragma unroll
      for (int j = 0; j < 2; j++)
        acc1[i][j] = __builtin_amdgcn_mfma_f32_16x16x32_f16(aH[i], bH[j],
                                                            acc1[i][j], 0, 0, 0);
#pragma unroll
    for (int i = 0; i < 4; i++)
#pragma unroll
      for (int j = 0; j < 2; j++)
        acc2[i][j] = __builtin_amdgcn_mfma_f32_16x16x32_f16(aH[i], bL[j],
                                                            acc2[i][j], 0, 0, 0);
    __builtin_amdgcn_s_setprio(0);
  };
  auto ph3 = [&](f16x8 (&bH)[2]) {
    __builtin_amdgcn_s_setprio(1);
#pragma unroll
    for (int i = 0; i < 4; i++)
#pragma unroll
      for (int j = 0; j < 2; j++)
        acc2[i][j] = __builtin_amdgcn_mfma_f32_16x16x32_f16(aL[i], bH[j],
                                                            acc2[i][j], 0, 0, 0);
    __builtin_amdgcn_s_setprio(0);
  };

#define SB0 __builtin_amdgcn_sched_barrier(0)

  // ---- prologue: stage k=0,1; load B(0); publish buf0.
  stageNext(lds0);                   // S0: 2
  loadBNext(b0H, b0L);               // L0: 4  (6 outstanding)
  stageNext(lds1);                   // S1: 2  (8)
  asm volatile("s_waitcnt vmcnt(6)" ::: "memory");  // retire S0
  __builtin_amdgcn_s_barrier();
  SB0;
  // invariant entering iter 0: outstanding L(0)4, S(1)2

  short *p0 = lds0, *p1 = lds1, *p2 = lds2;  // p_i = buf[(ks+i)%3]
  for (int ks = 0; ks <= KSTEPS - 4; ks += 2) {
    // ---- iter ks (even): compute with B set0, load B(ks+1) into set1
    ldsRead(p0);                     // 8 ds_read_b128 (buf[ks])
    loadBNext(b1H, b1L);             // +4 -> L(ks)4,S(ks+1)2,L(ks+1)4
    stageNext(p2);                   // +2 -> +S(ks+2)2 = 12
    SB0;
    asm volatile("s_waitcnt vmcnt(8)" ::: "memory");  // B(ks) ready
    SB0;
    ph12(b0H, b0L);                  // 16 MFMA (lgkm for aH auto-inserted)
    ph3(b0H);                        // 8 MFMA
    SB0;
    asm volatile("s_waitcnt vmcnt(6)" ::: "memory");  // retire S(ks+1)
    __builtin_amdgcn_s_barrier();    // publish buf[ks+1]; 6 in flight
    SB0;
    // ---- iter ks+1 (odd): compute with set1, load B(ks+2) into set0
    ldsRead(p1);                     // buf[ks+1]
    loadBNext(b0H, b0L);
    stageNext(p0);                   // buf[ks+3] == physical p0 (safe: reads
    SB0;                             // of buf[ks] finished before last barrier)
    asm volatile("s_waitcnt vmcnt(8)" ::: "memory");
    SB0;
    ph12(b1H, b1L);
    ph3(b1H);
    SB0;
    asm volatile("s_waitcnt vmcnt(6)" ::: "memory");  // retire S(ks+2)
    __builtin_amdgcn_s_barrier();    // publish buf[ks+2]
    SB0;
    short* t = p0; p0 = p2; p2 = p1; p1 = t;  // (p0,p1,p2) <- (p2,p0,p1)
  }

  // ---- peeled ks = KSTEPS-2 (even): loadB only, no stage
  ldsRead(p0);
  loadBNext(b1H, b1L);               // -> L(ks)4,S(ks+1)2,L(ks+1)4 = 10
  SB0;
  asm volatile("s_waitcnt vmcnt(6)" ::: "memory");   // B(ks) ready
  SB0;
  ph12(b0H, b0L);
  ph3(b0H);
  SB0;
  asm volatile("s_waitcnt vmcnt(4)" ::: "memory");   // retire S(KSTEPS-1)
  __builtin_amdgcn_s_barrier();      // publish buf[KSTEPS-1]
  SB0;
  // ---- peeled ks = KSTEPS-1 (odd): compute only
  ldsRead(p1);
  SB0;
  asm volatile("s_waitcnt vmcnt(0)" ::: "memory");   // B(KSTEPS-1) ready
  SB0;
  ph12(b1H, b1L);
  ph3(b1H);

  // epilogue: combine accs, bias + per-column activation + clip.
  // C/D map col=lane&15, row=quad*4+reg (m89-verified).
  // OUT_F16 path writes PACKED layout (next layer's A): chunkrow=row>>4,
  // kstep=col>>5, lane'=((col>>3)&3)*16 + (row&15), j'=col&7.
#pragma unroll
  for (int j = 0; j < 2; j++) {
    int col = blockN + wave * 32 + j * 16 + m16;
    float b = bias[col];
    float m = mo[col];
    int a = aid[col];
    size_t kbase = OUT_F16 ? ((size_t)(col >> 5) * MCH) * 512 +
                                 (size_t)((col >> 3) & 3) * 128 + (col & 7)
                           : 0;
#pragma unroll
    for (int i = 0; i < 4; i++) {
#pragma unroll
      for (int r = 0; r < 4; r++) {
        int row = blockM + i * 16 + quad * 4 + r;
        float s = acc1[i][j][r] + acc2[i][j][r] * INV_LO_SCALE;
        float v = rand_act(s + b, a, m);
        if (OUT_F16) {
          unsigned short h, l;
          split_h(v, h, l);
          size_t pidx = kbase + (size_t)(row >> 4) * 512 + (row & 15) * 8;
          Ch[pidx] = h;
          Cl[pidx] = l;
        } else {
          Cf[(size_t)row * N + col] = v;
        }
      }
    }
  }
}

extern "C" void kernel_launch(void* const* d_in, const int* in_sizes, int n_in,
                              void* d_out, int out_size, void* d_ws,
                              size_t ws_size, hipStream_t stream) {
  (void)in_sizes; (void)n_in; (void)out_size; (void)ws_size;

  const float* x     = (const float*)d_in[0];
  const float* W_in  = (const float*)d_in[1];
  const float* b_in  = (const float*)d_in[2];
  const float* Wh[6] = {(const float*)d_in[3], (const float*)d_in[4],
                        (const float*)d_in[5], (const float*)d_in[6],
                        (const float*)d_in[7], (const float*)d_in[8]};
  const float* bh    = (const float*)d_in[9];
  const float* W_out = (const float*)d_in[10];
  const float* b_out = (const float*)d_in[11];
  const float* mo_in = (const float*)d_in[12];
  const float* mo_h  = (const float*)d_in[13];
  const float* mo_out= (const float*)d_in[14];
  const int* aid_in  = (const int*)d_in[15];
  const int* aid_h   = (const int*)d_in[16];
  const int* aid_out = (const int*)d_in[17];

  const int hin[6] = {XDIM, XDIM, 2 * XDIM, XDIM, 2 * XDIM, XDIM};

  // workspace layout (~264 MB); each tensor = hi plane then lo plane (packed)
  char* p = (char*)d_ws;
  auto take = [&](size_t elems) {
    short* q = (short*)p;
    p += elems * 2 * 2;  // hi + lo, 2B each
    return q;
  };
  short* x_s = take((size_t)BDIM * INDIM);
  size_t xpl = (size_t)BDIM * INDIM;
  short* w_in_s = take((size_t)XDIM * INDIM);
  size_t wpl_in = (size_t)XDIM * INDIM;
  short* w_h_s[6];
  size_t wpl_h[6];
  for (int i = 0; i < 6; i++) {
    wpl_h[i] = (size_t)XDIM * hin[i];
    w_h_s[i] = take(wpl_h[i]);
  }
  short* w_out_s = take((size_t)OUTDIM * XDIM);
  size_t wpl_out = (size_t)OUTDIM * XDIM;
  const size_t apl = (size_t)BDIM * XDIM;  // activation plane
  short* actA = take(apl);
  short* actB = take(apl);
  short* actC = take(apl);

  // 1) pack x -> hi/lo fp16 packed
  pack_x<<<dim3(INDIM / 32, BDIM / 64), dim3(256), 0, stream>>>(
      x, (unsigned short*)x_s, (unsigned short*)(x_s + xpl), INDIM);
  // 2) pack all weights: W(K,N) -> packed BT(rows=N, Kdim=K) hi/lo
  pack_w<<<dim3(XDIM / 32, INDIM / 32), dim3(32, 8), 0, stream>>>(
      W_in, (unsigned short*)w_in_s, (unsigned short*)(w_in_s + wpl_in), INDIM,
      XDIM);
  for (int i = 0; i < 6; i++)
    pack_w<<<dim3(XDIM / 32, hin[i] / 32), dim3(32, 8), 0, stream>>>(
        Wh[i], (unsigned short*)w_h_s[i],
        (unsigned short*)(w_h_s[i] + wpl_h[i]), hin[i], XDIM);
  pack_w<<<dim3(OUTDIM / 32, XDIM / 32), dim3(32, 8), 0, stream>>>(
      W_out, (unsigned short*)w_out_s, (unsigned short*)(w_out_s + wpl_out),
      XDIM, OUTDIM);

  // 3) GEMM chain with 3 rotating activation buffers
  auto G = [&](const short* A1, size_t a1pl, const short* A2, size_t a2pl,
               const short* W, size_t wpl, const float* bi, const float* m,
               const int* a, short* Cb, float* Cf, int N, int K, int Ks) {
    dim3 grid(N / 128, BDIM / 64);
    const short* A2h = A2;
    const short* A2l = A2 ? A2 + a2pl : nullptr;
    if (Cb)
      gemm_split_act<true><<<grid, 256, 0, stream>>>(
          A1, A1 + a1pl, A2h, A2l, W, W + wpl, bi, m, a, (unsigned short*)Cb,
          (unsigned short*)(Cb + apl), nullptr, N, K, Ks);
    else
      gemm_split_act<false><<<grid, 256, 0, stream>>>(
          A1, A1 + a1pl, A2h, A2l, W, W + wpl, bi, m, a, nullptr, nullptr, Cf,
          N, K, Ks);
  };

  // input layer: outs[0]=actA
  G(x_s, xpl, nullptr, 0, w_in_s, wpl_in, b_in, mo_in, aid_in, actA, nullptr,
    XDIM, INDIM, INDIM);
  // L0: outs[1]=actB
  G(actA, apl, nullptr, 0, w_h_s[0], wpl_h[0], bh + 0 * XDIM, mo_h + 0 * XDIM,
    aid_h + 0 * XDIM, actB, nullptr, XDIM, XDIM, XDIM);
  // L1: outs[2]=actC
  G(actB, apl, nullptr, 0, w_h_s[1], wpl_h[1], bh + 1 * XDIM, mo_h + 1 * XDIM,
    aid_h + 1 * XDIM, actC, nullptr, XDIM, XDIM, XDIM);
  // L2 (concat outs2,outs1): outs[3]=actA
  G(actC, apl, actB, apl, w_h_s[2], wpl_h[2], bh + 2 * XDIM, mo_h + 2 * XDIM,
    aid_h + 2 * XDIM, actA, nullptr, XDIM, 2 * XDIM, XDIM);
  // L3: outs[4]=actB
  G(actA, apl, nullptr, 0, w_h_s[3], wpl_h[3], bh + 3 * XDIM, mo_h + 3 * XDIM,
    aid_h + 3 * XDIM, actB, nullptr, XDIM, XDIM, XDIM);
  // L4 (concat outs4,outs3): outs[5]=actC
  G(actB, apl, actA, apl, w_h_s[4], wpl_h[4], bh + 4 * XDIM, mo_h + 4 * XDIM,
    aid_h + 4 * XDIM, actC, nullptr, XDIM, 2 * XDIM, XDIM);
  // L5: outs[6]=actB
  G(actC, apl, nullptr, 0, w_h_s[5], wpl_h[5], bh + 5 * XDIM, mo_h + 5 * XDIM,
    aid_h + 5 * XDIM, actB, nullptr, XDIM, XDIM, XDIM);
  // output layer -> d_out (fp32, row-major)
  G(actB, apl, nullptr, 0, w_out_s, wpl_out, b_out, mo_out, aid_out, nullptr,
    (float*)d_out, OUTDIM, XDIM, XDIM);
}

// Round 3
// 1148.723 us; speedup vs baseline: 1.1766x; 1.0668x over previous
//
#include <hip/hip_runtime.h>
#include <stdint.h>
#include <string.h>

// Problem dims (fixed by the reference)
#define BDIM   4096
#define INDIM  1024
#define XDIM   2048
#define OUTDIM 512
#define MCH    (BDIM / 16)   // 256 row-chunks along M for packed activations

#define LO_SCALE 2048.0f         // 2^11: lifts fp16 lo-plane out of subnormals
#define INV_LO_SCALE (1.0f / 2048.0f)

typedef _Float16 f16x8 __attribute__((ext_vector_type(8)));
typedef float f32x4 __attribute__((ext_vector_type(4)));
typedef unsigned short u16x8 __attribute__((ext_vector_type(8)));
typedef unsigned short u16x4 __attribute__((ext_vector_type(4)));

__device__ __forceinline__ unsigned short h2u(_Float16 h) {
  unsigned short u;
  memcpy(&u, &h, 2);
  return u;
}

// split f32 into hi fp16 + scaled-lo fp16 (combined ~22 mantissa bits)
__device__ __forceinline__ void split_h(float v, unsigned short& h,
                                        unsigned short& l) {
  _Float16 hh = (_Float16)v;                       // RTNE
  float r = v - (float)hh;                         // exact
  _Float16 ll = (_Float16)(r * LO_SCALE);          // |r|*2^11 <= |v|, no inf
  h = h2u(hh);
  l = h2u(ll);
}

// async global->LDS, 16B per lane; LDS dest wave-uniform base + lane*16
__device__ __forceinline__ void gld_lds16(const void* g, void* l) {
  __builtin_amdgcn_global_load_lds(
      (const __attribute__((address_space(1))) uint32_t*)g,
      (__attribute__((address_space(3))) uint32_t*)l, 16, 0, 0);
}

// fused RandomActivation + clip (relu/sigmoid/tanh/leaky(.1)/selu), libm-grade
__device__ __forceinline__ float rand_act(float v, int a, float mo) {
  float r;
  if (a == 0) {
    r = fmaxf(v, 0.0f);
  } else if (a == 1) {
    r = 1.0f / (1.0f + expf(-v));
  } else if (a == 2) {
    r = tanhf(v);
  } else if (a == 3) {
    r = (v >= 0.0f) ? v : 0.1f * v;
  } else {  // selu (matches jax: scale * where(v>0, v, alpha*expm1(v)))
    r = (v > 0.0f) ? 1.0507009873554805f * v
                   : 1.7580993408473766f * expm1f(v);
  }
  return fminf(r, mo);
}

// ---------------------------------------------------------------------------
// PACKED LAYOUT: tensor X[rows][K] is stored as
//   packed[k/32][row/16][lane(64)][8 halfs],
// lane = quad*16 + m16 holding X[chunkrow*16 + m16][kstep*32 + quad*8 + j].
// Each (kstep,chunk) = contiguous 1 KB: staging DMA is consecutive-lane-
// contiguous AND compute ds_read_b128 is contiguous (zero conflicts).
// Concat along K = packed tensors back-to-back.
// ---------------------------------------------------------------------------

// x[BDIM][Kin] f32 row-major -> packed hi/lo planes. grid(Kin/32, BDIM/64)x256
__global__ void pack_x(const float* __restrict__ s,
                       unsigned short* __restrict__ dh,
                       unsigned short* __restrict__ dl, int Kin) {
  int ks = blockIdx.x;
  int mblk = blockIdx.y;
  int cc = threadIdx.x >> 6;        // chunk within 64-row group
  int lane = threadIdx.x & 63;
  int m16 = lane & 15, quad = lane >> 4;
  int row = mblk * 64 + cc * 16 + m16;
  const float* src = s + (size_t)row * Kin + ks * 32 + quad * 8;
  size_t o = ((size_t)ks * MCH + mblk * 4 + cc) * 512 + lane * 8;
  float4 v0 = *(const float4*)src;
  float4 v1 = *(const float4*)(src + 4);
  float vs[8] = {v0.x, v0.y, v0.z, v0.w, v1.x, v1.y, v1.z, v1.w};
  u16x8 vh, vl;
#pragma unroll
  for (int j = 0; j < 8; j++) {
    unsigned short h, l;
    split_h(vs[j], h, l);
    vh[j] = h;
    vl[j] = l;
  }
  *(u16x8*)(dh + o) = vh;
  *(u16x8*)(dl + o) = vl;
}

// W[K][N] f32 row-major -> packed-BT hi/lo (rows=N, Kdim=K).
// grid(N/32, K/32), block(32,8).
__global__ void pack_w(const float* __restrict__ W,
                       unsigned short* __restrict__ dh,
                       unsigned short* __restrict__ dl, int K, int N) {
  __shared__ float t[32][33];       // t[k'][n']
  int n0 = blockIdx.x * 32, k0 = blockIdx.y * 32;
  int tx = threadIdx.x, ty = threadIdx.y;
#pragma unroll
  for (int i = 0; i < 32; i += 8)
    t[ty + i][tx] = W[(size_t)(k0 + ty + i) * N + n0 + tx];
  __syncthreads();
  int tt = ty * 32 + tx;            // 0..255
  int ci = tt >> 7;                 // n-chunk 0/1
  int rem = tt & 127;
  int lane = rem >> 1;
  int j4 = (rem & 1) * 4;
  int m16 = lane & 15, quad = lane >> 4;
  size_t o = ((size_t)(k0 >> 5) * (N >> 4) + (n0 >> 4) + ci) * 512 +
             lane * 8 + j4;
  u16x4 vh, vl;
#pragma unroll
  for (int jj = 0; jj < 4; jj++) {
    float v = t[quad * 8 + j4 + jj][ci * 16 + m16];
    unsigned short h, l;
    split_h(v, h, l);
    vh[jj] = h;
    vl[jj] = l;
  }
  *(u16x4*)(dh + o) = vh;
  *(u16x4*)(dl + o) = vl;
}

// C[M,N] = act( A[M,K] @ BT[N,K]^T + bias ), split-fp16 (3-term) precision.
// acc1 = hi*hi; acc2 = hi*lo' + lo'*hi at scale 2^11. Final = acc1+acc2/2^11.
//
// Round-12 structure (R2 post-mortem applied):
//  - UNIFIED REG BUDGET: 4 waves/SIMD needs arch VGPR + AGPR <= 128; acc=64
//    AGPR, so arch VGPR must stay <= 64 (R2's 80 dropped to 3 blocks/CU).
//    aH/aL reads staggered (aH dies before aL born); 32-bit offsets.
//  - WINDOW = 2 K-steps per barrier (BK=64): one s_barrier + one manual
//    vmcnt per 48 MFMAs (R2 paid it per 24). 2 LDS buffers x 16 KB.
//  - Ledger per window: enter [L(k0)4]; issue L(k1)4 + S(w+1)4; compiler
//    auto-waits vmcnt(8) before sub0 B-use; SB0; L(k2)4; auto vmcnt(8)
//    before sub1; manual vmcnt(4)+s_barrier (retires S, L(k2) crosses).
//    Never drains to 0; stage has a full window before its barrier.
//  - linear block order (proven: FETCH ~313 MB, B re-reads L3-warm).
// Block tile 64x128, BK=32, 4 waves (wave-tile 64x32). Grid (N/128, M/64).
template <bool OUT_F16>
__global__ __launch_bounds__(256, 4) void gemm_split_act(
    const short* __restrict__ A1h, const short* __restrict__ A1l,
    const short* __restrict__ A2h, const short* __restrict__ A2l,
    const short* __restrict__ BTh, const short* __restrict__ BTl,
    const float* __restrict__ bias, const float* __restrict__ mo,
    const int* __restrict__ aid, unsigned short* __restrict__ Ch,
    unsigned short* __restrict__ Cl, float* __restrict__ Cf, int N, int K,
    int Ksplit) {
  __shared__ short lds0[2 * 8 * 512];   // 16 KB: [sub][8 chunks][512]
  __shared__ short lds1[2 * 8 * 512];

  const int tid = threadIdx.x;
  const int lane = tid & 63;
  const int wave = tid >> 6;        // 0..3 = n-strip of wave
  const int m16 = lane & 15, quad = lane >> 4;

  const int blockN = blockIdx.x * 128;   // linear order (proven locality)
  const int blockM = blockIdx.y * 64;

  f32x4 acc1[4][2];  // hi*hi
  f32x4 acc2[4][2];  // (hi*lo' + lo'*hi), scale 2^11
#pragma unroll
  for (int i = 0; i < 4; i++)
#pragma unroll
    for (int j = 0; j < 2; j++) {
      acc1[i][j] = (f32x4){0.f, 0.f, 0.f, 0.f};
      acc2[i][j] = (f32x4){0.f, 0.f, 0.f, 0.f};
    }

  const int KSTEPS = K >> 5;        // 32/64/128 — always even, >= 32
  const int W = KSTEPS >> 1;        // windows (16/32/64)
  const int KS1W = (Ksplit >> 5) >> 1;  // part-1 windows (always even splits)

  // ---- staging state: one window = 2 k-steps = 4 DMAs/wave (1 KB each)
  const short* sAh = A1h;
  const short* sAl = A1l;
  const unsigned aBase0 = (unsigned)((blockM >> 4) * 512 + lane * 8);
  unsigned aOff = aBase0;
  int stageW = 0;
  auto stageNext = [&](short* dst) {
#pragma unroll
    for (int sub = 0; sub < 2; sub++) {
#pragma unroll
      for (int s = 0; s < 2; s++) {
        int g = wave * 2 + s;          // 0..7
        const short* plane = (g < 4) ? sAh : sAl;
        gld_lds16(plane + aOff + sub * (MCH * 512) + (g & 3) * 512,
                  dst + sub * 4096 + g * 512);
      }
    }
    aOff += 2u * (MCH * 512);
    if (++stageW == KS1W) { sAh = A2h; sAl = A2l; aOff = aBase0; }
  };

  // ---- B-load state (4 x 16B loads per wave per K-step), 32-bit offset
  unsigned bOff = (unsigned)(((blockN >> 4) + wave * 2) * 512 + lane * 8);
  const unsigned bStride = (unsigned)N * 32;
  auto loadBNext = [&](f16x8 (&bH)[2], f16x8 (&bL)[2]) {
    bH[0] = *(const f16x8*)(BTh + bOff);
    bH[1] = *(const f16x8*)(BTh + bOff + 512);
    bL[0] = *(const f16x8*)(BTl + bOff);
    bL[1] = *(const f16x8*)(BTl + bOff + 512);
    bOff += bStride;
  };

  f16x8 b0H[2], b0L[2], b1H[2], b1L[2];

  // one K-sub-step: aH reads -> 16 MFMA -> aL reads -> 8 MFMA (staggered
  // liveness keeps arch VGPR <= 64)
  auto computeSub = [&](const short* buf, int sub, f16x8 (&bH)[2],
                        f16x8 (&bL)[2]) {
    f16x8 aH[4];
#pragma unroll
    for (int t = 0; t < 4; t++)
      aH[t] = *(const f16x8*)&buf[sub * 4096 + t * 512 + lane * 8];
    __builtin_amdgcn_s_setprio(1);
#pragma unroll
    for (int i = 0; i < 4; i++)
#pragma unroll
      for (int j = 0; j < 2; j++)
        acc1[i][j] = __builtin_amdgcn_mfma_f32_16x16x32_f16(aH[i], bH[j],
                                                            acc1[i][j], 0, 0, 0);
#pragma unroll
    for (int i = 0; i < 4; i++)
#pragma unroll
      for (int j = 0; j < 2; j++)
        acc2[i][j] = __builtin_amdgcn_mfma_f32_16x16x32_f16(aH[i], bL[j],
                                                            acc2[i][j], 0, 0, 0);
    __builtin_amdgcn_s_setprio(0);
    f16x8 aL[4];
#pragma unroll
    for (int t = 0; t < 4; t++)
      aL[t] = *(const f16x8*)&buf[sub * 4096 + (4 + t) * 512 + lane * 8];
    __builtin_amdgcn_s_setprio(1);
#pragma unroll
    for (int i = 0; i < 4; i++)
#pragma unroll
      for (int j = 0; j < 2; j++)
        acc2[i][j] = __builtin_amdgcn_mfma_f32_16x16x32_f16(aL[i], bH[j],
                                                            acc2[i][j], 0, 0, 0);
    __builtin_amdgcn_s_setprio(0);
  };

#define SB0 __builtin_amdgcn_sched_barrier(0)

  // ---- prologue: stage window 0 -> lds0; load B(0); publish lds0.
  stageNext(lds0);                   // S0: 4
  loadBNext(b0H, b0L);               // L(k0): 4  (8 outstanding)
  asm volatile("s_waitcnt vmcnt(4)" ::: "memory");  // S0 done; L(k0) flies
  __builtin_amdgcn_s_barrier();
  SB0;
  // invariant entering window w: outstanding [L(k0) 4]; buf[w] published

  short* cur = lds0;
  short* oth = lds1;
  for (int w = 0; w < W - 1; ++w) {
    loadBNext(b1H, b1L);             // L(k1) -> set1
    stageNext(oth);                  // S(w+1) -> other buffer (safe: its
                                     // reads retired before last barrier)
    computeSub(cur, 0, b0H, b0L);    // auto vmcnt(8) before B(k0) use
    SB0;                             // pin: S issued before L(k2)
    loadBNext(b0H, b0L);             // L(k2) -> set0 (set0 consumed above)
    computeSub(cur, 1, b1H, b1L);    // auto vmcnt(8) before B(k1) use
    SB0;
    asm volatile("s_waitcnt vmcnt(4)" ::: "memory");  // retire S(w+1);
    __builtin_amdgcn_s_barrier();    // publish buf[w+1]; L(k2) crosses
    SB0;
    short* t = cur; cur = oth; oth = t;
  }

  // ---- tail window W-1: no stage, no L(k2); compiler auto-waits.
  loadBNext(b1H, b1L);
  computeSub(cur, 0, b0H, b0L);
  computeSub(cur, 1, b1H, b1L);

  // epilogue: combine accs, bias + per-column activation + clip.
  // C/D map col=lane&15, row=quad*4+reg (m89-verified).
  // OUT_F16 path writes PACKED layout (next layer's A): chunkrow=row>>4,
  // kstep=col>>5, lane'=((col>>3)&3)*16 + (row&15), j'=col&7.
#pragma unroll
  for (int j = 0; j < 2; j++) {
    int col = blockN + wave * 32 + j * 16 + m16;
    float b = bias[col];
    float m = mo[col];
    int a = aid[col];
    size_t kbase = OUT_F16 ? ((size_t)(col >> 5) * MCH) * 512 +
                                 (size_t)((col >> 3) & 3) * 128 + (col & 7)
                           : 0;
#pragma unroll
    for (int i = 0; i < 4; i++) {
#pragma unroll
      for (int r = 0; r < 4; r++) {
        int row = blockM + i * 16 + quad * 4 + r;
        float s = acc1[i][j][r] + acc2[i][j][r] * INV_LO_SCALE;
        float v = rand_act(s + b, a, m);
        if (OUT_F16) {
          unsigned short h, l;
          split_h(v, h, l);
          size_t pidx = kbase + (size_t)(row >> 4) * 512 + (row & 15) * 8;
          Ch[pidx] = h;
          Cl[pidx] = l;
        } else {
          Cf[(size_t)row * N + col] = v;
        }
      }
    }
  }
}

extern "C" void kernel_launch(void* const* d_in, const int* in_sizes, int n_in,
                              void* d_out, int out_size, void* d_ws,
                              size_t ws_size, hipStream_t stream) {
  (void)in_sizes; (void)n_in; (void)out_size; (void)ws_size;

  const float* x     = (const float*)d_in[0];
  const float* W_in  = (const float*)d_in[1];
  const float* b_in  = (const float*)d_in[2];
  const float* Wh[6] = {(const float*)d_in[3], (const float*)d_in[4],
                        (const float*)d_in[5], (const float*)d_in[6],
                        (const float*)d_in[7], (const float*)d_in[8]};
  const float* bh    = (const float*)d_in[9];
  const float* W_out = (const float*)d_in[10];
  const float* b_out = (const float*)d_in[11];
  const float* mo_in = (const float*)d_in[12];
  const float* mo_h  = (const float*)d_in[13];
  const float* mo_out= (const float*)d_in[14];
  const int* aid_in  = (const int*)d_in[15];
  const int* aid_h   = (const int*)d_in[16];
  const int* aid_out = (const int*)d_in[17];

  const int hin[6] = {XDIM, XDIM, 2 * XDIM, XDIM, 2 * XDIM, XDIM};

  // workspace layout (~264 MB); each tensor = hi plane then lo plane (packed)
  char* p = (char*)d_ws;
  auto take = [&](size_t elems) {
    short* q = (short*)p;
    p += elems * 2 * 2;  // hi + lo, 2B each
    return q;
  };
  short* x_s = take((size_t)BDIM * INDIM);
  size_t xpl = (size_t)BDIM * INDIM;
  short* w_in_s = take((size_t)XDIM * INDIM);
  size_t wpl_in = (size_t)XDIM * INDIM;
  short* w_h_s[6];
  size_t wpl_h[6];
  for (int i = 0; i < 6; i++) {
    wpl_h[i] = (size_t)XDIM * hin[i];
    w_h_s[i] = take(wpl_h[i]);
  }
  short* w_out_s = take((size_t)OUTDIM * XDIM);
  size_t wpl_out = (size_t)OUTDIM * XDIM;
  const size_t apl = (size_t)BDIM * XDIM;  // activation plane
  short* actA = take(apl);
  short* actB = take(apl);
  short* actC = take(apl);

  // 1) pack x -> hi/lo fp16 packed
  pack_x<<<dim3(INDIM / 32, BDIM / 64), dim3(256), 0, stream>>>(
      x, (unsigned short*)x_s, (unsigned short*)(x_s + xpl), INDIM);
  // 2) pack all weights: W(K,N) -> packed BT(rows=N, Kdim=K) hi/lo
  pack_w<<<dim3(XDIM / 32, INDIM / 32), dim3(32, 8), 0, stream>>>(
      W_in, (unsigned short*)w_in_s, (unsigned short*)(w_in_s + wpl_in), INDIM,
      XDIM);
  for (int i = 0; i < 6; i++)
    pack_w<<<dim3(XDIM / 32, hin[i] / 32), dim3(32, 8), 0, stream>>>(
        Wh[i], (unsigned short*)w_h_s[i],
        (unsigned short*)(w_h_s[i] + wpl_h[i]), hin[i], XDIM);
  pack_w<<<dim3(OUTDIM / 32, XDIM / 32), dim3(32, 8), 0, stream>>>(
      W_out, (unsigned short*)w_out_s, (unsigned short*)(w_out_s + wpl_out),
      XDIM, OUTDIM);

  // 3) GEMM chain with 3 rotating activation buffers
  auto G = [&](const short* A1, size_t a1pl, const short* A2, size_t a2pl,
               const short* W, size_t wpl, const float* bi, const float* m,
               const int* a, short* Cb, float* Cf, int N, int K, int Ks) {
    dim3 grid(N / 128, BDIM / 64);
    const short* A2h = A2;
    const short* A2l = A2 ? A2 + a2pl : nullptr;
    if (Cb)
      gemm_split_act<true><<<grid, 256, 0, stream>>>(
          A1, A1 + a1pl, A2h, A2l, W, W + wpl, bi, m, a, (unsigned short*)Cb,
          (unsigned short*)(Cb + apl), nullptr, N, K, Ks);
    else
      gemm_split_act<false><<<grid, 256, 0, stream>>>(
          A1, A1 + a1pl, A2h, A2l, W, W + wpl, bi, m, a, nullptr, nullptr, Cf,
          N, K, Ks);
  };

  // input layer: outs[0]=actA
  G(x_s, xpl, nullptr, 0, w_in_s, wpl_in, b_in, mo_in, aid_in, actA, nullptr,
    XDIM, INDIM, INDIM);
  // L0: outs[1]=actB
  G(actA, apl, nullptr, 0, w_h_s[0], wpl_h[0], bh + 0 * XDIM, mo_h + 0 * XDIM,
    aid_h + 0 * XDIM, actB, nullptr, XDIM, XDIM, XDIM);
  // L1: outs[2]=actC
  G(actB, apl, nullptr, 0, w_h_s[1], wpl_h[1], bh + 1 * XDIM, mo_h + 1 * XDIM,
    aid_h + 1 * XDIM, actC, nullptr, XDIM, XDIM, XDIM);
  // L2 (concat outs2,outs1): outs[3]=actA
  G(actC, apl, actB, apl, w_h_s[2], wpl_h[2], bh + 2 * XDIM, mo_h + 2 * XDIM,
    aid_h + 2 * XDIM, actA, nullptr, XDIM, 2 * XDIM, XDIM);
  // L3: outs[4]=actB
  G(actA, apl, nullptr, 0, w_h_s[3], wpl_h[3], bh + 3 * XDIM, mo_h + 3 * XDIM,
    aid_h + 3 * XDIM, actB, nullptr, XDIM, XDIM, XDIM);
  // L4 (concat outs4,outs3): outs[5]=actC
  G(actB, apl, actA, apl, w_h_s[4], wpl_h[4], bh + 4 * XDIM, mo_h + 4 * XDIM,
    aid_h + 4 * XDIM, actC, nullptr, XDIM, 2 * XDIM, XDIM);
  // L5: outs[6]=actB
  G(actC, apl, nullptr, 0, w_h_s[5], wpl_h[5], bh + 5 * XDIM, mo_h + 5 * XDIM,
    aid_h + 5 * XDIM, actB, nullptr, XDIM, XDIM, XDIM);
  // output layer -> d_out (fp32, row-major)
  G(actB, apl, nullptr, 0, w_out_s, wpl_out, b_out, mo_out, aid_out, nullptr,
    (float*)d_out, OUTDIM, XDIM, XDIM);
}